// Round 5
// baseline (1168.315 us; speedup 1.0000x reference)
//
#include <hip/hip_runtime.h>
#include <hip/hip_bf16.h>
#include <math.h>

#define NDIM 512
#define NB   128
#define NMAT 129
#define EPSF 1e-7f
#define MS  ((size_t)262144)   // matrix stride (floats) = 512*512
#define LTS ((size_t)32768)    // Lt stride per matrix (floats) = 64*512
#define PSTR ((size_t)524288)  // E2 plane stride (floats) = 512*512*2

// workspace layout (float offsets)
#define OFF_E   ((size_t)0)                    // 2 planes * 524288 = 1,048,576
#define OFF_WM  ((size_t)1048576)              // 262,144
#define OFF_IPR ((size_t)(OFF_WM + 262144))    // 65,536
#define OFF_LPR ((size_t)(OFF_IPR + 65536))    // 128
#define OFF_LD  ((size_t)(OFF_LPR + 128))      // 129 (pad to 1,377,792)
#define OFF_LT  ((size_t)1377792)              // 129*32768 = 4,227,072
#define OFF_MAT ((size_t)(OFF_LT + (size_t)NMAT*LTS))   // ~158 MB total

// ---------- fused prep: Wm (blocks 0..1023), E-IPF (1024..2047), Pr (2048..2175) ----------
__global__ __launch_bounds__(256) void k_prep(const float* __restrict__ Vc, const float* __restrict__ W,
                                              const float* __restrict__ Ec, const int* __restrict__ x,
                                              float* __restrict__ Wm, float* __restrict__ E2,
                                              float* __restrict__ invPr, float* __restrict__ logPr) {
  const int blk = blockIdx.x;
  if (blk < 1024) {
    // Wm = sym(tril(sigmoid(W), -1))
    int idx = blk*256 + threadIdx.x;
    int i = idx >> 9, j = idx & 511;
    float v = 0.f;
    if (i > j)      v = 1.f / (1.f + expf(-W[i*NDIM + j]));
    else if (i < j) v = 1.f / (1.f + expf(-W[j*NDIM + i]));
    Wm[idx] = v;
  } else if (blk < 2048) {
    // per-(i,j) 2x2 IPF on E; output xi-planes with xj interleaved
    int idx = (blk-1024)*256 + threadIdx.x;   // i*512 + j
    int i = idx >> 9, j = idx & 511;
    float4 ec = reinterpret_cast<const float4*>(Ec)[idx];
    float e00 = expf(ec.x), e01 = expf(ec.y), e10 = expf(ec.z), e11 = expf(ec.w);
    float s = e00 + e01 + e10 + e11;
    float inv = 1.f / s;
    e00 *= inv; e01 *= inv; e10 *= inv; e11 *= inv;
    // V rows i and j inline (identical ops to softmax kernel)
    float vi0 = Vc[2*i], vi1 = Vc[2*i+1];
    float mi = fmaxf(vi0, vi1);
    float ei0 = expf(vi0 - mi), ei1 = expf(vi1 - mi);
    float A0 = ei0/(ei0+ei1), A1 = ei1/(ei0+ei1);
    float vj0 = Vc[2*j], vj1 = Vc[2*j+1];
    float mj = fmaxf(vj0, vj1);
    float ej0 = expf(vj0 - mj), ej1 = expf(vj1 - mj);
    float B0 = ej0/(ej0+ej1), B1 = ej1/(ej0+ej1);
    for (int t = 0; t < 10; ++t) {
      float rm0 = e00 + e01 + EPSF, rm1 = e10 + e11 + EPSF;
      float cm0 = e00 + e10 + EPSF, cm1 = e01 + e11 + EPSF;
      float f0 = A0 / rm0, f1 = A1 / rm1;
      e00 *= f0; e01 *= f0; e10 *= f1; e11 *= f1;
      float g0 = B0 / cm0, g1 = B1 / cm1;
      e00 *= g0; e10 *= g0; e01 *= g1; e11 *= g1;
      float ss = e00 + e01 + e10 + e11 + EPSF;
      float iv = 1.f / ss;
      e00 *= iv; e01 *= iv; e10 *= iv; e11 *= iv;
    }
    if (i == j) { e00 = 0.f; e01 = 0.f; e10 = 0.f; e11 = 0.f; }
    e00 = fminf(fmaxf(e00, 0.f), 1.f);
    e01 = fminf(fmaxf(e01, 0.f), 1.f);
    e10 = fminf(fmaxf(e10, 0.f), 1.f);
    e11 = fminf(fmaxf(e11, 0.f), 1.f);
    reinterpret_cast<float2*>(E2)[idx]        = make_float2(e00, e01);  // plane xi=0
    reinterpret_cast<float2*>(E2 + PSTR)[idx] = make_float2(e10, e11);  // plane xi=1
  } else {
    // Pr, invPr, sum(log Pr) per batch
    const int b = blk - 2048;
    const int tid = threadIdx.x;
    float acc = 0.f;
    for (int ii = tid; ii < NDIM; ii += 256) {
      const int xv = x[b*NDIM + ii];
      float v0 = Vc[2*ii], v1 = Vc[2*ii+1];
      float mx = fmaxf(v0, v1);
      float e0 = expf(v0 - mx), e1 = expf(v1 - mx);
      float p = (xv ? e1 : e0) / (e0 + e1);
      invPr[b*NDIM + ii] = 1.f / p;
      acc += logf(p);
    }
    for (int off = 32; off > 0; off >>= 1) acc += __shfl_down(acc, off, 64);
    __shared__ float sw[4];
    if ((tid & 63) == 0) sw[tid >> 6] = acc;
    __syncthreads();
    if (tid == 0) logPr[b] = sw[0] + sw[1] + sw[2] + sw[3];
  }
}

// ---------- build 511x511 minors: one wave per row, 8 elems/lane, no LDS/barriers ----------
__global__ __launch_bounds__(512) void k_build(const int* __restrict__ x, const float* __restrict__ E2,
                                               const float* __restrict__ Wm, const float* __restrict__ invPr,
                                               float* __restrict__ Mall) {
  const int b = blockIdx.x;            // 0..128 (fast -> L2 locality on E2/Wm row)
  const int tid = threadIdx.x;
  const int w = tid >> 6;              // wave 0..7
  const int l = tid & 63;
  const int i = blockIdx.y*8 + w;      // 0..511 ; i==0 -> writes pad row 511
  const int j0 = 8*l;
  if (i == 0) {
    float* Mrow = Mall + (size_t)b*MS + (size_t)511*NDIM;
    #pragma unroll
    for (int k = 0; k < 8; ++k) Mrow[j0+k] = (j0+k == 511) ? 1.f : 0.f;
    return;
  }
  float* Mrow = Mall + (size_t)b*MS + (size_t)(i-1)*NDIM;
  float4 wma = *(const float4*)(Wm + i*NDIM + j0);
  float4 wmb = *(const float4*)(Wm + i*NDIM + j0 + 4);
  float wp[8];
  if (b < NB) {
    const int xi = x[b*NDIM + i];                 // wave-uniform
    const float ipi = invPr[b*NDIM + i];          // wave-uniform
    int4 xja = *(const int4*)(x + b*NDIM + j0);
    int4 xjb = *(const int4*)(x + b*NDIM + j0 + 4);
    float4 ipa = *(const float4*)(invPr + b*NDIM + j0);
    float4 ipb = *(const float4*)(invPr + b*NDIM + j0 + 4);
    const float* pe = E2 + (size_t)xi*PSTR + ((size_t)i << 10) + 16*l;
    float4 e0 = *(const float4*)(pe);
    float4 e1 = *(const float4*)(pe + 4);
    float4 e2 = *(const float4*)(pe + 8);
    float4 e3 = *(const float4*)(pe + 12);
    float ev[8];
    ev[0] = xja.x ? e0.y : e0.x;
    ev[1] = xja.y ? e0.w : e0.z;
    ev[2] = xja.z ? e1.y : e1.x;
    ev[3] = xja.w ? e1.w : e1.z;
    ev[4] = xjb.x ? e2.y : e2.x;
    ev[5] = xjb.y ? e2.w : e2.z;
    ev[6] = xjb.z ? e3.y : e3.x;
    ev[7] = xjb.w ? e3.w : e3.z;
    float ip[8] = {ipa.x,ipa.y,ipa.z,ipa.w,ipb.x,ipb.y,ipb.z,ipb.w};
    float wm[8] = {wma.x,wma.y,wma.z,wma.w,wmb.x,wmb.y,wmb.z,wmb.w};
    #pragma unroll
    for (int k = 0; k < 8; ++k) wp[k] = wm[k]*ev[k]*ipi*ip[k];
  } else {
    wp[0]=wma.x; wp[1]=wma.y; wp[2]=wma.z; wp[3]=wma.w;
    wp[4]=wmb.x; wp[5]=wmb.y; wp[6]=wmb.z; wp[7]=wmb.w;
  }
  float rs = wp[0]+wp[1]+wp[2]+wp[3]+wp[4]+wp[5]+wp[6]+wp[7];
  #pragma unroll
  for (int m = 1; m < 64; m <<= 1) rs += __shfl_xor(rs, m, 64);  // all-lane row sum
  #pragma unroll
  for (int k = 0; k < 8; ++k) {
    const int j = j0 + k;
    float val = (j == i) ? rs : -wp[k];
    int col = j - 1;
    if (j == 0) { col = 511; val = 0.f; }   // pad column
    Mrow[col] = val;
  }
}

// ---------- panel factorization + fused TRSM ----------
template<int KK>
struct PanelStep {
  static __device__ __forceinline__ void run(float (&a)[64], float (*pivrow)[72],
                                             int t, int m, float& logp) {
    float* pb = pivrow[KK & 1];
    if (t == KK) {
      #pragma unroll
      for (int c = 0; c < 16; ++c)
        *(float4*)(pb + c*4) = make_float4(a[c*4], a[c*4+1], a[c*4+2], a[c*4+3]);
      pb[64] = 1.0f / a[KK];
      logp += logf(fabsf(a[KK]));
    }
    __syncthreads();
    if (t > KK && t < m) {
      const float l = a[KK] * pb[64];
      a[KK] = l;
      #pragma unroll
      for (int c = KK + 1; c < 64; ++c)
        a[c] -= l * pb[c];
    }
    PanelStep<KK + 1>::run(a, pivrow, t, m, logp);
  }
};
template<>
struct PanelStep<64> {
  static __device__ __forceinline__ void run(float (&)[64], float (*)[72], int, int, float&) {}
};

__global__ __launch_bounds__(512) void k_panel(float* __restrict__ Mall, float* __restrict__ Lt,
                                               float* __restrict__ logdets, int k0, int mrem) {
  const int b = blockIdx.x;
  float* __restrict__ M = Mall + (size_t)b*MS;
  float* __restrict__ L = Lt + (size_t)b*LTS;
  const int t = threadIdx.x;
  const int m = NDIM - k0;          // 512,448,...,64
  __shared__ float pivrow[2][72];
  __shared__ float Ls[64][65];      // Ls[p][kk] = L11[kk][p] (upper region unused junk)
  float a[64];
  if (t < m) {
    const float* row = M + (size_t)(k0+t)*NDIM + k0;
    #pragma unroll
    for (int c4 = 0; c4 < 16; ++c4) {
      float4 v = *(const float4*)(row + c4*4);
      a[c4*4+0]=v.x; a[c4*4+1]=v.y; a[c4*4+2]=v.z; a[c4*4+3]=v.w;
    }
  }
  float logp = 0.f;
  PanelStep<0>::run(a, pivrow, t, m, logp);
  // write transposed panel: Lt[c][r]; lanes over r -> coalesced
  if (t < m) {
    #pragma unroll
    for (int c = 0; c < 64; ++c) L[(size_t)c*NDIM + t] = a[c];
  }
  if (t < 64) {
    float v = logp;
    for (int off = 32; off > 0; off >>= 1) v += __shfl_down(v, off, 64);
    if (t == 0) logdets[b] = (k0 == 0) ? v : (logdets[b] + v);
  }
  if (mrem > 0) {
    // stage L11 rows into LDS (full row incl. U junk; TRSM reads only p<kk part)
    if (t < 64) {
      #pragma unroll
      for (int p = 0; p < 64; ++p) Ls[p][t] = a[p];
    }
    __syncthreads();
    // TRSM: one column per thread (mrem <= 448 < 512)
    if (t < mrem) {
      const int col = k0 + 64 + t;
      float u[64];
      #pragma unroll
      for (int r = 0; r < 64; ++r) u[r] = M[(size_t)(k0+r)*NDIM + col];
      #pragma unroll
      for (int p = 0; p < 63; ++p) {
        const float lv = u[p];
        #pragma unroll
        for (int kk = p+1; kk < 64; ++kk)
          u[kk] -= Ls[p][kk] * lv;
      }
      #pragma unroll
      for (int r = 1; r < 64; ++r) M[(size_t)(k0+r)*NDIM + col] = u[r];
    }
  }
}

// ---------- trailing update: C -= L21 * U12, 64x64 tile, 4x4/thread ----------
__global__ __launch_bounds__(256, 4) void k_gemm(float* __restrict__ Mall, const float* __restrict__ Lt,
                                                 int k0) {
  const int b = blockIdx.x;
  float* __restrict__ M = Mall + (size_t)b*MS;
  const float* __restrict__ L = Lt + (size_t)b*LTS;
  __shared__ float As[64][68];     // As[p][r] = L21[r][p]
  __shared__ float Bs[64][68];     // Bs[p][c] = U12[p][c]
  const int tid = threadIdx.x;
  const int tx = tid & 15, ty = tid >> 4;
  const int rowbase = 64 + blockIdx.y*64;   // panel-local row of C tile
  const int colbase = 64 + blockIdx.z*64;   // panel-local col
  #pragma unroll
  for (int i = 0; i < 4; ++i) {
    int q = tid + 256*i;           // 1024 float4
    int p = q >> 4, f = q & 15;
    *(float4*)&As[p][f*4] = *(const float4*)&L[(size_t)p*NDIM + rowbase + f*4];
    *(float4*)&Bs[p][f*4] = *(const float4*)&M[(size_t)(k0+p)*NDIM + (k0+colbase) + f*4];
  }
  float* Crow = M + (size_t)(k0+rowbase+ty*4)*NDIM + (k0+colbase+tx*4);
  float4 c0 = *(float4*)(Crow + 0*NDIM);
  float4 c1 = *(float4*)(Crow + 1*NDIM);
  float4 c2 = *(float4*)(Crow + 2*NDIM);
  float4 c3 = *(float4*)(Crow + 3*NDIM);
  __syncthreads();
  #pragma unroll
  for (int p = 0; p < 64; ++p) {
    const float4 av = *(const float4*)&As[p][ty*4];
    const float4 bv = *(const float4*)&Bs[p][tx*4];
    c0.x -= av.x*bv.x; c0.y -= av.x*bv.y; c0.z -= av.x*bv.z; c0.w -= av.x*bv.w;
    c1.x -= av.y*bv.x; c1.y -= av.y*bv.y; c1.z -= av.y*bv.z; c1.w -= av.y*bv.w;
    c2.x -= av.z*bv.x; c2.y -= av.z*bv.y; c2.z -= av.z*bv.z; c2.w -= av.z*bv.w;
    c3.x -= av.w*bv.x; c3.y -= av.w*bv.y; c3.z -= av.w*bv.z; c3.w -= av.w*bv.w;
  }
  *(float4*)(Crow + 0*NDIM) = c0;
  *(float4*)(Crow + 1*NDIM) = c1;
  *(float4*)(Crow + 2*NDIM) = c2;
  *(float4*)(Crow + 3*NDIM) = c3;
}

// ---------- final combine ----------
__global__ void k_final(const float* __restrict__ logPr, const float* __restrict__ logdets,
                        float* __restrict__ out) {
  int t = threadIdx.x;
  if (t < NB) out[t] = logPr[t] + logdets[t] - logdets[NB];
}

extern "C" void kernel_launch(void* const* d_in, const int* in_sizes, int n_in,
                              void* d_out, int out_size, void* d_ws, size_t ws_size,
                              hipStream_t stream) {
  const int*   x  = (const int*)  d_in[0];
  const float* W  = (const float*)d_in[1];
  const float* Vc = (const float*)d_in[2];
  const float* Ec = (const float*)d_in[3];
  float* out = (float*)d_out;
  float* ws  = (float*)d_ws;
  (void)in_sizes; (void)n_in; (void)out_size; (void)ws_size;  // needs ~158 MiB of ws

  float* Mat = ws + OFF_MAT;
  float* Lt  = ws + OFF_LT;
  float* Ld  = ws + OFF_LD;

  k_prep<<<2176, 256, 0, stream>>>(Vc, W, Ec, x, ws + OFF_WM, ws + OFF_E,
                                   ws + OFF_IPR, ws + OFF_LPR);
  dim3 gb(NMAT, 64);
  k_build<<<gb, 512, 0, stream>>>(x, ws + OFF_E, ws + OFF_WM, ws + OFF_IPR, Mat);

  for (int s = 0; s < 8; ++s) {
    const int k0 = s*64;
    const int mrem = NDIM - k0 - 64;
    k_panel<<<NMAT, 512, 0, stream>>>(Mat, Lt, Ld, k0, mrem);
    if (mrem > 0) {
      const int nt = mrem/64;
      dim3 gg(NMAT, nt, nt);
      k_gemm<<<gg, 256, 0, stream>>>(Mat, Lt, k0);
    }
  }
  k_final<<<1, 128, 0, stream>>>(ws + OFF_LPR, Ld, out);
}

// Round 6
// 750.643 us; speedup vs baseline: 1.5564x; 1.5564x over previous
//
#include <hip/hip_runtime.h>
#include <hip/hip_bf16.h>
#include <math.h>

#define NDIM 512
#define NB   128
#define NMAT 129
#define EPSF 1e-7f
#define MS  ((size_t)262144)   // matrix stride (floats) = 512*512
#define LTS ((size_t)32768)    // Lt stride per matrix (floats) = 64*512
#define PSTR ((size_t)524288)  // E2 plane stride (floats) = 512*512*2

// workspace layout (float offsets)
#define OFF_E   ((size_t)0)                    // 2 planes * 524288 = 1,048,576
#define OFF_WM  ((size_t)1048576)              // 262,144
#define OFF_IPR ((size_t)(OFF_WM + 262144))    // 65,536
#define OFF_LPR ((size_t)(OFF_IPR + 65536))    // 128
#define OFF_LD  ((size_t)(OFF_LPR + 128))      // 129 (pad to 1,377,792)
#define OFF_LT  ((size_t)1377792)              // 129*32768 = 4,227,072
#define OFF_MAT ((size_t)(OFF_LT + (size_t)NMAT*LTS))   // ~158 MB total

// ---------- fused prep: Wm (blocks 0..1023), E-IPF (1024..2047), Pr (2048..2175) ----------
__global__ __launch_bounds__(256) void k_prep(const float* __restrict__ Vc, const float* __restrict__ W,
                                              const float* __restrict__ Ec, const int* __restrict__ x,
                                              float* __restrict__ Wm, float* __restrict__ E2,
                                              float* __restrict__ invPr, float* __restrict__ logPr) {
  const int blk = blockIdx.x;
  if (blk < 1024) {
    int idx = blk*256 + threadIdx.x;
    int i = idx >> 9, j = idx & 511;
    float v = 0.f;
    if (i > j)      v = 1.f / (1.f + expf(-W[i*NDIM + j]));
    else if (i < j) v = 1.f / (1.f + expf(-W[j*NDIM + i]));
    Wm[idx] = v;
  } else if (blk < 2048) {
    int idx = (blk-1024)*256 + threadIdx.x;   // i*512 + j
    int i = idx >> 9, j = idx & 511;
    float4 ec = reinterpret_cast<const float4*>(Ec)[idx];
    float e00 = expf(ec.x), e01 = expf(ec.y), e10 = expf(ec.z), e11 = expf(ec.w);
    float s = e00 + e01 + e10 + e11;
    float inv = 1.f / s;
    e00 *= inv; e01 *= inv; e10 *= inv; e11 *= inv;
    float vi0 = Vc[2*i], vi1 = Vc[2*i+1];
    float mi = fmaxf(vi0, vi1);
    float ei0 = expf(vi0 - mi), ei1 = expf(vi1 - mi);
    float A0 = ei0/(ei0+ei1), A1 = ei1/(ei0+ei1);
    float vj0 = Vc[2*j], vj1 = Vc[2*j+1];
    float mj = fmaxf(vj0, vj1);
    float ej0 = expf(vj0 - mj), ej1 = expf(vj1 - mj);
    float B0 = ej0/(ej0+ej1), B1 = ej1/(ej0+ej1);
    for (int t = 0; t < 10; ++t) {
      float rm0 = e00 + e01 + EPSF, rm1 = e10 + e11 + EPSF;
      float cm0 = e00 + e10 + EPSF, cm1 = e01 + e11 + EPSF;
      float f0 = A0 / rm0, f1 = A1 / rm1;
      e00 *= f0; e01 *= f0; e10 *= f1; e11 *= f1;
      float g0 = B0 / cm0, g1 = B1 / cm1;
      e00 *= g0; e10 *= g0; e01 *= g1; e11 *= g1;
      float ss = e00 + e01 + e10 + e11 + EPSF;
      float iv = 1.f / ss;
      e00 *= iv; e01 *= iv; e10 *= iv; e11 *= iv;
    }
    if (i == j) { e00 = 0.f; e01 = 0.f; e10 = 0.f; e11 = 0.f; }
    e00 = fminf(fmaxf(e00, 0.f), 1.f);
    e01 = fminf(fmaxf(e01, 0.f), 1.f);
    e10 = fminf(fmaxf(e10, 0.f), 1.f);
    e11 = fminf(fmaxf(e11, 0.f), 1.f);
    reinterpret_cast<float2*>(E2)[idx]        = make_float2(e00, e01);  // plane xi=0
    reinterpret_cast<float2*>(E2 + PSTR)[idx] = make_float2(e10, e11);  // plane xi=1
  } else {
    const int b = blk - 2048;
    const int tid = threadIdx.x;
    float acc = 0.f;
    for (int ii = tid; ii < NDIM; ii += 256) {
      const int xv = x[b*NDIM + ii];
      float v0 = Vc[2*ii], v1 = Vc[2*ii+1];
      float mx = fmaxf(v0, v1);
      float e0 = expf(v0 - mx), e1 = expf(v1 - mx);
      float p = (xv ? e1 : e0) / (e0 + e1);
      invPr[b*NDIM + ii] = 1.f / p;
      acc += logf(p);
    }
    for (int off = 32; off > 0; off >>= 1) acc += __shfl_down(acc, off, 64);
    __shared__ float sw[4];
    if ((tid & 63) == 0) sw[tid >> 6] = acc;
    __syncthreads();
    if (tid == 0) logPr[b] = sw[0] + sw[1] + sw[2] + sw[3];
  }
}

// ---------- build 511x511 minors: one wave per row, 8 elems/lane, no LDS/barriers ----------
__global__ __launch_bounds__(512) void k_build(const int* __restrict__ x, const float* __restrict__ E2,
                                               const float* __restrict__ Wm, const float* __restrict__ invPr,
                                               float* __restrict__ Mall) {
  const int b = blockIdx.x;            // 0..128 (fast -> L2 locality on E2/Wm row)
  const int tid = threadIdx.x;
  const int w = tid >> 6;              // wave 0..7
  const int l = tid & 63;
  const int i = blockIdx.y*8 + w;      // 0..511 ; i==0 -> writes pad row 511
  const int j0 = 8*l;
  if (i == 0) {
    float* Mrow = Mall + (size_t)b*MS + (size_t)511*NDIM;
    #pragma unroll
    for (int k = 0; k < 8; ++k) Mrow[j0+k] = (j0+k == 511) ? 1.f : 0.f;
    return;
  }
  float* Mrow = Mall + (size_t)b*MS + (size_t)(i-1)*NDIM;
  float4 wma = *(const float4*)(Wm + i*NDIM + j0);
  float4 wmb = *(const float4*)(Wm + i*NDIM + j0 + 4);
  float wp[8];
  if (b < NB) {
    const int xi = x[b*NDIM + i];                 // wave-uniform
    const float ipi = invPr[b*NDIM + i];          // wave-uniform
    int4 xja = *(const int4*)(x + b*NDIM + j0);
    int4 xjb = *(const int4*)(x + b*NDIM + j0 + 4);
    float4 ipa = *(const float4*)(invPr + b*NDIM + j0);
    float4 ipb = *(const float4*)(invPr + b*NDIM + j0 + 4);
    const float* pe = E2 + (size_t)xi*PSTR + ((size_t)i << 10) + 16*l;
    float4 e0 = *(const float4*)(pe);
    float4 e1 = *(const float4*)(pe + 4);
    float4 e2 = *(const float4*)(pe + 8);
    float4 e3 = *(const float4*)(pe + 12);
    float ev[8];
    ev[0] = xja.x ? e0.y : e0.x;
    ev[1] = xja.y ? e0.w : e0.z;
    ev[2] = xja.z ? e1.y : e1.x;
    ev[3] = xja.w ? e1.w : e1.z;
    ev[4] = xjb.x ? e2.y : e2.x;
    ev[5] = xjb.y ? e2.w : e2.z;
    ev[6] = xjb.z ? e3.y : e3.x;
    ev[7] = xjb.w ? e3.w : e3.z;
    float ip[8] = {ipa.x,ipa.y,ipa.z,ipa.w,ipb.x,ipb.y,ipb.z,ipb.w};
    float wm[8] = {wma.x,wma.y,wma.z,wma.w,wmb.x,wmb.y,wmb.z,wmb.w};
    #pragma unroll
    for (int k = 0; k < 8; ++k) wp[k] = wm[k]*ev[k]*ipi*ip[k];
  } else {
    wp[0]=wma.x; wp[1]=wma.y; wp[2]=wma.z; wp[3]=wma.w;
    wp[4]=wmb.x; wp[5]=wmb.y; wp[6]=wmb.z; wp[7]=wmb.w;
  }
  float rs = wp[0]+wp[1]+wp[2]+wp[3]+wp[4]+wp[5]+wp[6]+wp[7];
  #pragma unroll
  for (int m = 1; m < 64; m <<= 1) rs += __shfl_xor(rs, m, 64);  // all-lane row sum
  #pragma unroll
  for (int k = 0; k < 8; ++k) {
    const int j = j0 + k;
    float val = (j == i) ? rs : -wp[k];
    int col = j - 1;
    if (j == 0) { col = 511; val = 0.f; }   // pad column
    Mrow[col] = val;
  }
}

// ---------- panel: wave-0 in-register shuffle-LU of A11, then barrier-free L21 solve ----------
// Wave 0: lane l holds row l of the 64-wide panel; pivot row broadcast via __shfl.
template<int KK>
struct WLU {
  static __device__ __forceinline__ void run(float (&a)[64], int l, float& logp,
                                             float (*pb)[68], float* invLDS) {
    float piv = __shfl(a[KK], KK, 64);
    float inv = 1.0f / piv;
    logp += logf(fabsf(piv));            // all lanes accumulate identical sum
    if (l == 0) invLDS[KK] = inv;
    const float mfac = (l > KK) ? a[KK] * inv : 0.0f;
    if (l > KK) a[KK] = mfac;
    #pragma unroll
    for (int c = KK + 1; c < 64; ++c) {
      float pc = __shfl(a[c], KK, 64);
      a[c] -= mfac * pc;                 // no-op for l <= KK (mfac == 0)
    }
    WLU<KK + 1>::run(a, l, logp, pb, invLDS);
  }
};
template<>
struct WLU<64> {
  static __device__ __forceinline__ void run(float (&)[64], int, float&, float (*)[68], float*) {}
};

// Rows >= 64: apply all 64 panel updates back-to-back, no barriers.
template<int KK>
struct SolveStep {
  static __device__ __forceinline__ void run(float (&a)[64], const float (*pb)[68],
                                             const float* invLDS) {
    const float lkk = a[KK] * invLDS[KK];
    a[KK] = lkk;
    #pragma unroll
    for (int c = KK + 1; c < 64; ++c)
      a[c] -= lkk * pb[KK][c];           // broadcast LDS read (all lanes same addr)
    SolveStep<KK + 1>::run(a, pb, invLDS);
  }
};
template<>
struct SolveStep<64> {
  static __device__ __forceinline__ void run(float (&)[64], const float (*)[68], const float*) {}
};

__global__ __launch_bounds__(512) void k_panel(float* __restrict__ Mall, float* __restrict__ Lt,
                                               float* __restrict__ logdets, int k0) {
  const int b = blockIdx.x;
  float* __restrict__ M = Mall + (size_t)b*MS;
  float* __restrict__ L = Lt + (size_t)b*LTS;
  const int t = threadIdx.x;
  const int m = NDIM - k0;          // 512,448,...,64
  __shared__ float pb[64][68];      // pivot rows (U rows of A11 LU)
  __shared__ float invLDS[64];
  float a[64];
  if (t < m) {
    const float* row = M + (size_t)(k0+t)*NDIM + k0;
    #pragma unroll
    for (int c4 = 0; c4 < 16; ++c4) {
      float4 v = *(const float4*)(row + c4*4);
      a[c4*4+0]=v.x; a[c4*4+1]=v.y; a[c4*4+2]=v.z; a[c4*4+3]=v.w;
    }
  }
  if (t < 64) {
    float logp = 0.f;
    WLU<0>::run(a, t, logp, pb, invLDS);
    // dump pivot rows to LDS for the L21 solve
    #pragma unroll
    for (int c = 0; c < 64; ++c) pb[t][c] = a[c];
    if (t == 0) logdets[b] = (k0 == 0) ? logp : (logdets[b] + logp);
  }
  __syncthreads();
  if (t >= 64 && t < m) {
    SolveStep<0>::run(a, pb, invLDS);
  }
  // write transposed panel: Lt[c][r]; lanes over r -> coalesced
  if (t < m) {
    #pragma unroll
    for (int c = 0; c < 64; ++c) L[(size_t)c*NDIM + t] = a[c];
  }
}

// ---------- TRSM: U12 = L11^{-1} A12, column-parallel, L11 broadcast from LDS ----------
__global__ __launch_bounds__(128) void k_u(float* __restrict__ Mall, const float* __restrict__ Lt,
                                           int k0, int mrem) {
  const int b = blockIdx.x;
  float* __restrict__ M = Mall + (size_t)b*MS;
  const float* __restrict__ L = Lt + (size_t)b*LTS;
  __shared__ float Ls[64][68];     // Ls[p][kk] = L[kk][p]
  const int tid = threadIdx.x;
  #pragma unroll
  for (int i = 0; i < 8; ++i) {
    int q = tid + 128*i;           // 1024 float4
    int p = q >> 4, f = q & 15;
    *(float4*)&Ls[p][f*4] = *(const float4*)&L[(size_t)p*NDIM + f*4];
  }
  __syncthreads();
  const int c = blockIdx.y*128 + tid;
  if (c < mrem) {
    const int col = k0 + 64 + c;
    float u[64];
    #pragma unroll
    for (int r = 0; r < 64; ++r) u[r] = M[(size_t)(k0+r)*NDIM + col];
    #pragma unroll
    for (int p = 0; p < 63; ++p) {
      const float lv = u[p];
      #pragma unroll
      for (int kk = p+1; kk < 64; ++kk)
        u[kk] -= Ls[p][kk] * lv;
    }
    #pragma unroll
    for (int r = 1; r < 64; ++r) M[(size_t)(k0+r)*NDIM + col] = u[r];
  }
}

// ---------- trailing update: C -= L21 * U12, 64x64 tile, 4x4/thread ----------
__global__ __launch_bounds__(256, 4) void k_gemm(float* __restrict__ Mall, const float* __restrict__ Lt,
                                                 int k0) {
  const int b = blockIdx.x;
  float* __restrict__ M = Mall + (size_t)b*MS;
  const float* __restrict__ L = Lt + (size_t)b*LTS;
  __shared__ float As[64][68];     // As[p][r] = L21[r][p]
  __shared__ float Bs[64][68];     // Bs[p][c] = U12[p][c]
  const int tid = threadIdx.x;
  const int tx = tid & 15, ty = tid >> 4;
  const int rowbase = 64 + blockIdx.y*64;   // panel-local row of C tile
  const int colbase = 64 + blockIdx.z*64;   // panel-local col
  #pragma unroll
  for (int i = 0; i < 4; ++i) {
    int q = tid + 256*i;           // 1024 float4
    int p = q >> 4, f = q & 15;
    *(float4*)&As[p][f*4] = *(const float4*)&L[(size_t)p*NDIM + rowbase + f*4];
    *(float4*)&Bs[p][f*4] = *(const float4*)&M[(size_t)(k0+p)*NDIM + (k0+colbase) + f*4];
  }
  float* Crow = M + (size_t)(k0+rowbase+ty*4)*NDIM + (k0+colbase+tx*4);
  float4 c0 = *(float4*)(Crow + 0*NDIM);
  float4 c1 = *(float4*)(Crow + 1*NDIM);
  float4 c2 = *(float4*)(Crow + 2*NDIM);
  float4 c3 = *(float4*)(Crow + 3*NDIM);
  __syncthreads();
  #pragma unroll
  for (int p = 0; p < 64; ++p) {
    const float4 av = *(const float4*)&As[p][ty*4];
    const float4 bv = *(const float4*)&Bs[p][tx*4];
    c0.x -= av.x*bv.x; c0.y -= av.x*bv.y; c0.z -= av.x*bv.z; c0.w -= av.x*bv.w;
    c1.x -= av.y*bv.x; c1.y -= av.y*bv.y; c1.z -= av.y*bv.z; c1.w -= av.y*bv.w;
    c2.x -= av.z*bv.x; c2.y -= av.z*bv.y; c2.z -= av.z*bv.z; c2.w -= av.z*bv.w;
    c3.x -= av.w*bv.x; c3.y -= av.w*bv.y; c3.z -= av.w*bv.z; c3.w -= av.w*bv.w;
  }
  *(float4*)(Crow + 0*NDIM) = c0;
  *(float4*)(Crow + 1*NDIM) = c1;
  *(float4*)(Crow + 2*NDIM) = c2;
  *(float4*)(Crow + 3*NDIM) = c3;
}

// ---------- final combine ----------
__global__ void k_final(const float* __restrict__ logPr, const float* __restrict__ logdets,
                        float* __restrict__ out) {
  int t = threadIdx.x;
  if (t < NB) out[t] = logPr[t] + logdets[t] - logdets[NB];
}

extern "C" void kernel_launch(void* const* d_in, const int* in_sizes, int n_in,
                              void* d_out, int out_size, void* d_ws, size_t ws_size,
                              hipStream_t stream) {
  const int*   x  = (const int*)  d_in[0];
  const float* W  = (const float*)d_in[1];
  const float* Vc = (const float*)d_in[2];
  const float* Ec = (const float*)d_in[3];
  float* out = (float*)d_out;
  float* ws  = (float*)d_ws;
  (void)in_sizes; (void)n_in; (void)out_size; (void)ws_size;  // needs ~158 MiB of ws

  float* Mat = ws + OFF_MAT;
  float* Lt  = ws + OFF_LT;
  float* Ld  = ws + OFF_LD;

  k_prep<<<2176, 256, 0, stream>>>(Vc, W, Ec, x, ws + OFF_WM, ws + OFF_E,
                                   ws + OFF_IPR, ws + OFF_LPR);
  dim3 gb(NMAT, 64);
  k_build<<<gb, 512, 0, stream>>>(x, ws + OFF_E, ws + OFF_WM, ws + OFF_IPR, Mat);

  for (int s = 0; s < 8; ++s) {
    const int k0 = s*64;
    const int mrem = NDIM - k0 - 64;
    k_panel<<<NMAT, 512, 0, stream>>>(Mat, Lt, Ld, k0);
    if (mrem > 0) {
      dim3 gu(NMAT, (mrem + 127)/128);
      k_u<<<gu, 128, 0, stream>>>(Mat, Lt, k0, mrem);
      const int nt = mrem/64;
      dim3 gg(NMAT, nt, nt);
      k_gemm<<<gg, 256, 0, stream>>>(Mat, Lt, k0);
    }
  }
  k_final<<<1, 128, 0, stream>>>(ws + OFF_LPR, Ld, out);
}